// Round 1
// baseline (918.363 us; speedup 1.0000x reference)
//
#include <hip/hip_runtime.h>
#include <hip/hip_bf16.h>

#define N_NODES 100000
#define N_EDGES 1200000
#define N_GRAPHS 512
#define HID 64
#define IN_DIM 16
#define EPS 1e-5f

// ---------------- CSR build ----------------

__global__ void deg_kernel(const int* __restrict__ ei, int* __restrict__ degInt) {
    int e = blockIdx.x * blockDim.x + threadIdx.x;
    if (e < N_EDGES) atomicAdd(&degInt[ei[N_EDGES + e]], 1);
}

__global__ void dis_kernel(const int* __restrict__ degInt, float* __restrict__ dis) {
    int n = blockIdx.x * blockDim.x + threadIdx.x;
    if (n < N_NODES) dis[n] = rsqrtf((float)(degInt[n] + 1));  // +1 self loop
}

__global__ void scan_local(const int* __restrict__ deg, int* __restrict__ off,
                           int* __restrict__ blockSums) {
    __shared__ int buf[1024];
    int t = threadIdx.x;
    int i = blockIdx.x * 1024 + t;
    int v = (i < N_NODES) ? deg[i] : 0;
    buf[t] = v;
    __syncthreads();
    for (int s = 1; s < 1024; s <<= 1) {
        int tmp = (t >= s) ? buf[t - s] : 0;
        __syncthreads();
        buf[t] += tmp;
        __syncthreads();
    }
    if (i < N_NODES) off[i + 1] = buf[t];  // inclusive within chunk
    if (t == 1023) blockSums[blockIdx.x] = buf[1023];
    if (i == 0) off[0] = 0;
}

__global__ void scan_blocksums(const int* __restrict__ blockSums,
                               int* __restrict__ blockCarry, int nb) {
    __shared__ int buf[128];
    int t = threadIdx.x;
    buf[t] = (t < nb) ? blockSums[t] : 0;
    __syncthreads();
    for (int s = 1; s < 128; s <<= 1) {
        int tmp = (t >= s) ? buf[t - s] : 0;
        __syncthreads();
        buf[t] += tmp;
        __syncthreads();
    }
    if (t < nb) blockCarry[t] = (t == 0) ? 0 : buf[t - 1];
}

__global__ void scan_add_carry(int* __restrict__ off, const int* __restrict__ blockCarry) {
    int i = blockIdx.x * blockDim.x + threadIdx.x;
    if (i < N_NODES) off[i + 1] += blockCarry[i >> 10];
}

__global__ void cursor_init(const int* __restrict__ off, int* __restrict__ cursor) {
    int n = blockIdx.x * blockDim.x + threadIdx.x;
    if (n < N_NODES) cursor[n] = off[n];
}

__global__ void csr_scatter(const int* __restrict__ ei, int* __restrict__ cursor,
                            int* __restrict__ csrSrc) {
    int e = blockIdx.x * blockDim.x + threadIdx.x;
    if (e < N_EDGES) {
        int s = ei[e];
        int d = ei[N_EDGES + e];
        int pos = atomicAdd(&cursor[d], 1);
        csrSrc[pos] = s;
    }
}

// ---------------- BN statistics ----------------

// stats over x [N,16]: sums/sumsq per feature
__global__ void stats_x(const float* __restrict__ x, float* __restrict__ sums,
                        float* __restrict__ sumsq) {
    __shared__ float ls[16], lq[16];
    int t = threadIdx.x;
    if (t < 16) { ls[t] = 0.f; lq[t] = 0.f; }
    __syncthreads();
    float s = 0.f, q = 0.f;
    const int total = N_NODES * IN_DIM;
    for (int i = blockIdx.x * blockDim.x + t; i < total; i += gridDim.x * blockDim.x) {
        float v = x[i];
        s += v; q += v * v;
    }
    int k = t & 15;  // stride divisible by 16 -> feature fixed per thread
    atomicAdd(&ls[k], s);
    atomicAdd(&lq[k], q);
    __syncthreads();
    if (t < 16) { atomicAdd(&sums[t], ls[t]); atomicAdd(&sumsq[t], lq[t]); }
}

// scale = gamma*rsqrt(var+eps); shift = beta - mean*scale
__global__ void finalize_bn(const float* __restrict__ sums, const float* __restrict__ sumsq,
                            const float* __restrict__ gamma, const float* __restrict__ beta,
                            float* __restrict__ scale, float* __restrict__ shift, int dim) {
    int t = threadIdx.x;
    if (t < dim) {
        const float invn = 1.0f / (float)N_NODES;
        float m = sums[t] * invn;
        float var = sumsq[t] * invn - m * m;
        float rs = rsqrtf(var + EPS);
        float sc = gamma[t] * rs;
        scale[t] = sc;
        shift[t] = beta[t] - m * sc;
    }
}

// ---------------- GEMMs (BN fused on input read) ----------------

#define GEMM_ROWS 32

// hw[n,f] = ((x[n,:]*scale+shift) @ W)[f] * dis[n]   (no relu: input BN)
__global__ void gemm16_kernel(const float* __restrict__ x, const float* __restrict__ W,
                              const float* __restrict__ scale, const float* __restrict__ shift,
                              const float* __restrict__ dis, float* __restrict__ hout) {
    __shared__ float Ws[IN_DIM][HID];
    __shared__ float xs[GEMM_ROWS][IN_DIM];
    int t = threadIdx.x, f = t & 63, nl = t >> 6;
    for (int i = t; i < IN_DIM * HID; i += 256) Ws[i >> 6][i & 63] = W[i];
    int base = blockIdx.x * GEMM_ROWS;
    for (int i = t; i < GEMM_ROWS * IN_DIM; i += 256) {
        int r = i >> 4, k = i & 15;
        int n = base + r;
        float v = 0.f;
        if (n < N_NODES) v = x[n * IN_DIM + k] * scale[k] + shift[k];
        xs[r][k] = v;
    }
    __syncthreads();
    float acc[8];
#pragma unroll
    for (int r = 0; r < 8; r++) acc[r] = 0.f;
    for (int k = 0; k < IN_DIM; k++) {
        float wk = Ws[k][f];
#pragma unroll
        for (int r = 0; r < 8; r++) acc[r] += xs[r * 4 + nl][k] * wk;
    }
#pragma unroll
    for (int r = 0; r < 8; r++) {
        int n = base + r * 4 + nl;
        if (n < N_NODES) hout[n * HID + f] = acc[r] * dis[n];
    }
}

// hw[n,f] = (relu(y[n,:]*scale+shift) @ W)[f] * dis[n]
__global__ void gemm64_kernel(const float* __restrict__ hin, const float* __restrict__ W,
                              const float* __restrict__ scale, const float* __restrict__ shift,
                              const float* __restrict__ dis, float* __restrict__ hout) {
    __shared__ float Ws[HID][HID];
    __shared__ float hs[GEMM_ROWS][HID];
    int t = threadIdx.x, f = t & 63, nl = t >> 6;
    for (int i = t; i < HID * HID; i += 256) Ws[i >> 6][i & 63] = W[i];
    int base = blockIdx.x * GEMM_ROWS;
    float sc = scale[f], sh = shift[f];
    for (int r = nl; r < GEMM_ROWS; r += 4) {
        int n = base + r;
        float v = 0.f;
        if (n < N_NODES) {
            v = hin[n * HID + f] * sc + sh;
            v = fmaxf(v, 0.f);
        }
        hs[r][f] = v;
    }
    __syncthreads();
    float acc[8];
#pragma unroll
    for (int r = 0; r < 8; r++) acc[r] = 0.f;
    for (int k = 0; k < HID; k++) {
        float wk = Ws[k][f];
#pragma unroll
        for (int r = 0; r < 8; r++) acc[r] += hs[r * 4 + nl][k] * wk;
    }
#pragma unroll
    for (int r = 0; r < 8; r++) {
        int n = base + r * 4 + nl;
        if (n < N_NODES) hout[n * HID + f] = acc[r] * dis[n];
    }
}

// ---------------- Aggregation (CSR gather) + BN stats ----------------

// y[n] = (hw[n] + sum_{j->n} hw[j]) * dis[n] + b ; accumulate sums/sumsq of y
__global__ void aggregate_kernel(const float* __restrict__ hw, const int* __restrict__ csrOff,
                                 const int* __restrict__ csrSrc, const float* __restrict__ dis,
                                 const float* __restrict__ bias, float* __restrict__ y,
                                 float* __restrict__ sums, float* __restrict__ sumsq) {
    int lane = threadIdx.x & 63;
    int wid = threadIdx.x >> 6;
    int wave = blockIdx.x * 4 + wid;
    int nwaves = gridDim.x * 4;
    float b = bias[lane];
    float s_acc = 0.f, q_acc = 0.f;
    for (int n = wave; n < N_NODES; n += nwaves) {
        float acc = hw[n * HID + lane];  // self loop
        int beg = csrOff[n], end = csrOff[n + 1];
        for (int e = beg; e < end; e += 64) {
            int cnt = min(64, end - e);
            int idx = (lane < cnt) ? csrSrc[e + lane] : 0;
            for (int j = 0; j < cnt; ++j) {
                int sj = __shfl(idx, j, 64);
                acc += hw[sj * HID + lane];
            }
        }
        float val = acc * dis[n] + b;
        y[n * HID + lane] = val;
        s_acc += val;
        q_acc += val * val;
    }
    __shared__ float ls[4][64], lq[4][64];
    ls[wid][lane] = s_acc;
    lq[wid][lane] = q_acc;
    __syncthreads();
    if (wid == 0) {
        float S = ls[0][lane] + ls[1][lane] + ls[2][lane] + ls[3][lane];
        float Q = lq[0][lane] + lq[1][lane] + lq[2][lane] + lq[3][lane];
        atomicAdd(&sums[lane], S);
        atomicAdd(&sumsq[lane], Q);
    }
}

// ---------------- Pool + head ----------------

#define POOL_CHUNK 256
__global__ void pool_kernel(const float* __restrict__ y, const int* __restrict__ batch,
                            const float* __restrict__ scale, const float* __restrict__ shift,
                            float* __restrict__ pool) {
    int f = threadIdx.x & 63;
    int nl = threadIdx.x >> 6;
    int base = blockIdx.x * POOL_CHUNK;
    int endn = min(base + POOL_CHUNK, N_NODES);
    float sc = scale[f], sh = shift[f];
    int g_cur = -1;
    float acc = 0.f;
    for (int n = base + nl; n < endn; n += 4) {
        int g = batch[n];
        float v = fmaxf(y[n * HID + f] * sc + sh, 0.f);
        if (g != g_cur) {
            if (g_cur >= 0) atomicAdd(&pool[g_cur * HID + f], acc);
            g_cur = g;
            acc = 0.f;
        }
        acc += v;
    }
    if (g_cur >= 0) atomicAdd(&pool[g_cur * HID + f], acc);
}

__global__ void cnt_kernel(const int* __restrict__ batch, float* __restrict__ cnt) {
    int i = blockIdx.x * blockDim.x + threadIdx.x;
    if (i < N_NODES) atomicAdd(&cnt[batch[i]], 1.0f);
}

__global__ void head_kernel(const float* __restrict__ pool, const float* __restrict__ cnt,
                            const float* __restrict__ Wc1, const float* __restrict__ bc1,
                            const float* __restrict__ Wc2, const float* __restrict__ bc2,
                            float* __restrict__ out) {
    int g = blockIdx.x;
    int f = threadIdx.x;  // 64 threads
    __shared__ float p[64], z[64];
    float c = fmaxf(cnt[g], 1.0f);
    p[f] = pool[g * HID + f] / c;
    __syncthreads();
    float acc = bc1[f];
    for (int k = 0; k < 64; k++) acc += p[k] * Wc1[k * 64 + f];
    z[f] = fmaxf(acc, 0.f);
    __syncthreads();
    if (f < 2) {
        float o = bc2[f];
        for (int k = 0; k < 64; k++) o += z[k] * Wc2[k * 2 + f];
        out[g * 2 + f] = o;
    }
}

// ---------------- launch ----------------

extern "C" void kernel_launch(void* const* d_in, const int* in_sizes, int n_in,
                              void* d_out, int out_size, void* d_ws, size_t ws_size,
                              hipStream_t stream) {
    const float* x      = (const float*)d_in[0];
    const int*   ei     = (const int*)d_in[1];
    const int*   batch  = (const int*)d_in[2];
    const float* bn_in_g = (const float*)d_in[3];
    const float* bn_in_b = (const float*)d_in[4];
    const float* W0 = (const float*)d_in[5];
    const float* b0 = (const float*)d_in[6];
    const float* g0 = (const float*)d_in[7];
    const float* be0 = (const float*)d_in[8];
    const float* W1 = (const float*)d_in[9];
    const float* b1 = (const float*)d_in[10];
    const float* g1 = (const float*)d_in[11];
    const float* be1 = (const float*)d_in[12];
    const float* W2 = (const float*)d_in[13];
    const float* b2 = (const float*)d_in[14];
    const float* g2 = (const float*)d_in[15];
    const float* be2 = (const float*)d_in[16];
    const float* Wc1 = (const float*)d_in[17];
    const float* bc1 = (const float*)d_in[18];
    const float* Wc2 = (const float*)d_in[19];
    const float* bc2 = (const float*)d_in[20];
    float* out = (float*)d_out;

    char* w = (char*)d_ws;
    size_t off = 0;
    auto take = [&](size_t bytes) {
        size_t r = off;
        off += (bytes + 255) & ~(size_t)255;
        return r;
    };
    // ---- zero region (one memset) ----
    int*   degInt = (int*)(w + take((size_t)N_NODES * 4));
    float* stats  = (float*)(w + take(4 * 256 * 4));  // slot l: [sums 64][sumsq 64][scale 64][shift 64]
    float* pool   = (float*)(w + take((size_t)N_GRAPHS * HID * 4));
    float* cnt    = (float*)(w + take((size_t)N_GRAPHS * 4));
    size_t zero_end = off;
    // ---- rest ----
    float* dis    = (float*)(w + take((size_t)N_NODES * 4));
    int* csrOff   = (int*)(w + take((size_t)(N_NODES + 1) * 4));
    int* cursor   = (int*)(w + take((size_t)N_NODES * 4));
    int* csrSrc   = (int*)(w + take((size_t)N_EDGES * 4));
    int* blockSums  = (int*)(w + take(256 * 4));
    int* blockCarry = (int*)(w + take(256 * 4));
    float* bufA   = (float*)(w + take((size_t)N_NODES * HID * 4));
    float* bufB   = (float*)(w + take((size_t)N_NODES * HID * 4));
    (void)ws_size; (void)n_in; (void)in_sizes; (void)out_size;

    hipMemsetAsync(w, 0, zero_end, stream);

    const int nbN   = (N_NODES + 255) / 256;
    const int nbE   = (N_EDGES + 255) / 256;
    const int nbScan = (N_NODES + 1023) / 1024;  // 98
    const int nbGemm = (N_NODES + GEMM_ROWS - 1) / GEMM_ROWS;

    // CSR build
    deg_kernel<<<nbE, 256, 0, stream>>>(ei, degInt);
    dis_kernel<<<nbN, 256, 0, stream>>>(degInt, dis);
    scan_local<<<nbScan, 1024, 0, stream>>>(degInt, csrOff, blockSums);
    scan_blocksums<<<1, 128, 0, stream>>>(blockSums, blockCarry, nbScan);
    scan_add_carry<<<nbN, 256, 0, stream>>>(csrOff, blockCarry);
    cursor_init<<<nbN, 256, 0, stream>>>(csrOff, cursor);
    csr_scatter<<<nbE, 256, 0, stream>>>(ei, cursor, csrSrc);

    // stats slot helpers
    float* s0 = stats + 0 * 256;
    float* s1 = stats + 1 * 256;
    float* s2 = stats + 2 * 256;
    float* s3 = stats + 3 * 256;

    // input BN
    stats_x<<<256, 256, 0, stream>>>(x, s0, s0 + 64);
    finalize_bn<<<1, 64, 0, stream>>>(s0, s0 + 64, bn_in_g, bn_in_b, s0 + 128, s0 + 192, IN_DIM);

    // layer 0
    gemm16_kernel<<<nbGemm, 256, 0, stream>>>(x, W0, s0 + 128, s0 + 192, dis, bufA);
    aggregate_kernel<<<1024, 256, 0, stream>>>(bufA, csrOff, csrSrc, dis, b0, bufB, s1, s1 + 64);
    finalize_bn<<<1, 64, 0, stream>>>(s1, s1 + 64, g0, be0, s1 + 128, s1 + 192, HID);

    // layer 1
    gemm64_kernel<<<nbGemm, 256, 0, stream>>>(bufB, W1, s1 + 128, s1 + 192, dis, bufA);
    aggregate_kernel<<<1024, 256, 0, stream>>>(bufA, csrOff, csrSrc, dis, b1, bufB, s2, s2 + 64);
    finalize_bn<<<1, 64, 0, stream>>>(s2, s2 + 64, g1, be1, s2 + 128, s2 + 192, HID);

    // layer 2
    gemm64_kernel<<<nbGemm, 256, 0, stream>>>(bufB, W2, s2 + 128, s2 + 192, dis, bufA);
    aggregate_kernel<<<1024, 256, 0, stream>>>(bufA, csrOff, csrSrc, dis, b2, bufB, s3, s3 + 64);
    finalize_bn<<<1, 64, 0, stream>>>(s3, s3 + 64, g2, be2, s3 + 128, s3 + 192, HID);

    // pool + head
    const int nbPool = (N_NODES + POOL_CHUNK - 1) / POOL_CHUNK;
    pool_kernel<<<nbPool, 256, 0, stream>>>(bufB, batch, s3 + 128, s3 + 192, pool);
    cnt_kernel<<<nbN, 256, 0, stream>>>(batch, cnt);
    head_kernel<<<N_GRAPHS, 64, 0, stream>>>(pool, cnt, Wc1, bc1, Wc2, bc2, out);
}

// Round 2
// 661.242 us; speedup vs baseline: 1.3888x; 1.3888x over previous
//
#include <hip/hip_runtime.h>
#include <hip/hip_bf16.h>

#define N_NODES 100000
#define N_EDGES 1200000
#define N_GRAPHS 512
#define HID 64
#define IN_DIM 16
#define EPS 1e-5f

// ---------------- CSR build ----------------

__global__ void deg_kernel(const int* __restrict__ ei, int* __restrict__ degInt) {
    int e = blockIdx.x * blockDim.x + threadIdx.x;
    if (e < N_EDGES) atomicAdd(&degInt[ei[N_EDGES + e]], 1);
}

// also computes dis = rsqrt(deg+1) (self loop included)
__global__ void scan_local(const int* __restrict__ deg, int* __restrict__ off,
                           int* __restrict__ blockSums, float* __restrict__ dis) {
    __shared__ int buf[1024];
    int t = threadIdx.x;
    int i = blockIdx.x * 1024 + t;
    int v = (i < N_NODES) ? deg[i] : 0;
    if (i < N_NODES) dis[i] = rsqrtf((float)(v + 1));
    buf[t] = v;
    __syncthreads();
    for (int s = 1; s < 1024; s <<= 1) {
        int tmp = (t >= s) ? buf[t - s] : 0;
        __syncthreads();
        buf[t] += tmp;
        __syncthreads();
    }
    if (i < N_NODES) off[i + 1] = buf[t];  // inclusive within chunk
    if (t == 1023) blockSums[blockIdx.x] = buf[1023];
    if (i == 0) off[0] = 0;
}

__global__ void scan_blocksums(const int* __restrict__ blockSums,
                               int* __restrict__ blockCarry, int nb) {
    __shared__ int buf[128];
    int t = threadIdx.x;
    buf[t] = (t < nb) ? blockSums[t] : 0;
    __syncthreads();
    for (int s = 1; s < 128; s <<= 1) {
        int tmp = (t >= s) ? buf[t - s] : 0;
        __syncthreads();
        buf[t] += tmp;
        __syncthreads();
    }
    if (t < nb) blockCarry[t] = (t == 0) ? 0 : buf[t - 1];
}

// also writes cursor (copy of final exclusive offsets)
__global__ void scan_add_carry(int* __restrict__ off, const int* __restrict__ blockCarry,
                               int* __restrict__ cursor) {
    int i = blockIdx.x * blockDim.x + threadIdx.x;
    if (i < N_NODES) {
        int v = off[i + 1] + blockCarry[i >> 10];
        off[i + 1] = v;
        if (i + 1 < N_NODES) cursor[i + 1] = v;
        if (i == 0) cursor[0] = 0;
    }
}

__global__ void csr_scatter(const int* __restrict__ ei, int* __restrict__ cursor,
                            int* __restrict__ csrSrc) {
    int e = blockIdx.x * blockDim.x + threadIdx.x;
    if (e < N_EDGES) {
        int s = ei[e];
        int d = ei[N_EDGES + e];
        int pos = atomicAdd(&cursor[d], 1);
        csrSrc[pos] = s;
    }
}

// ---------------- BN statistics ----------------

__global__ void stats_x(const float* __restrict__ x, float* __restrict__ sums,
                        float* __restrict__ sumsq) {
    __shared__ float ls[16], lq[16];
    int t = threadIdx.x;
    if (t < 16) { ls[t] = 0.f; lq[t] = 0.f; }
    __syncthreads();
    float s = 0.f, q = 0.f;
    const int total = N_NODES * IN_DIM;
    for (int i = blockIdx.x * blockDim.x + t; i < total; i += gridDim.x * blockDim.x) {
        float v = x[i];
        s += v; q += v * v;
    }
    int k = t & 15;
    atomicAdd(&ls[k], s);
    atomicAdd(&lq[k], q);
    __syncthreads();
    if (t < 16) { atomicAdd(&sums[t], ls[t]); atomicAdd(&sumsq[t], lq[t]); }
}

__global__ void finalize_bn(const float* __restrict__ sums, const float* __restrict__ sumsq,
                            const float* __restrict__ gamma, const float* __restrict__ beta,
                            float* __restrict__ scale, float* __restrict__ shift, int dim) {
    int t = threadIdx.x;
    if (t < dim) {
        const float invn = 1.0f / (float)N_NODES;
        float m = sums[t] * invn;
        float var = sumsq[t] * invn - m * m;
        float rs = rsqrtf(var + EPS);
        float sc = gamma[t] * rs;
        scale[t] = sc;
        shift[t] = beta[t] - m * sc;
    }
}

// ---------------- GEMMs (BN fused on input read) ----------------

#define GEMM_ROWS 32

// hw[n,f] = ((x[n,:]*scale+shift) @ W)[f] * dis[n]   (no relu: input BN)
__global__ void gemm16_kernel(const float* __restrict__ x, const float* __restrict__ W,
                              const float* __restrict__ scale, const float* __restrict__ shift,
                              const float* __restrict__ dis, float* __restrict__ hout) {
    __shared__ float Ws[IN_DIM][HID];
    __shared__ float xs[GEMM_ROWS][IN_DIM];
    int t = threadIdx.x, f = t & 63, nl = t >> 6;
    for (int i = t; i < IN_DIM * HID; i += 256) Ws[i >> 6][i & 63] = W[i];
    int base = blockIdx.x * GEMM_ROWS;
    for (int i = t; i < GEMM_ROWS * IN_DIM; i += 256) {
        int r = i >> 4, k = i & 15;
        int n = base + r;
        float v = 0.f;
        if (n < N_NODES) v = x[n * IN_DIM + k] * scale[k] + shift[k];
        xs[r][k] = v;
    }
    __syncthreads();
    float acc[8];
#pragma unroll
    for (int r = 0; r < 8; r++) acc[r] = 0.f;
    for (int k = 0; k < IN_DIM; k++) {
        float wk = Ws[k][f];
#pragma unroll
        for (int r = 0; r < 8; r++) acc[r] += xs[r * 4 + nl][k] * wk;
    }
#pragma unroll
    for (int r = 0; r < 8; r++) {
        int n = base + r * 4 + nl;
        if (n < N_NODES) hout[n * HID + f] = acc[r] * dis[n];
    }
}

// register-blocked: each thread computes 8 rows x 4 features
#define G64_ROWS 128
__global__ void gemm64_kernel(const float* __restrict__ hin, const float* __restrict__ W,
                              const float* __restrict__ scale, const float* __restrict__ shift,
                              const float* __restrict__ dis, float* __restrict__ hout) {
    __shared__ float Ws[HID * HID];          // [k][f], f contiguous
    __shared__ float hs[G64_ROWS][HID + 1];  // +1 pad: conflict-free column reads
    int t = threadIdx.x;
    int fg = t & 15;   // features fg*4 .. fg*4+3
    int rg = t >> 4;   // rows rg*8 .. rg*8+7
    int base = blockIdx.x * G64_ROWS;

    {
        const float4* W4 = (const float4*)W;
        float4* Ws4 = (float4*)Ws;
        for (int i = t; i < HID * HID / 4; i += 256) Ws4[i] = W4[i];
    }
    {
        const float4* hin4 = (const float4*)hin;
        const float4* sc4 = (const float4*)scale;
        const float4* sh4 = (const float4*)shift;
        for (int i = t; i < G64_ROWS * 16; i += 256) {
            int r = i >> 4, c = i & 15;
            int n = base + r;
            float4 v = make_float4(0.f, 0.f, 0.f, 0.f);
            if (n < N_NODES) {
                float4 h = hin4[n * 16 + c];
                float4 s = sc4[c], b = sh4[c];
                v.x = fmaxf(h.x * s.x + b.x, 0.f);
                v.y = fmaxf(h.y * s.y + b.y, 0.f);
                v.z = fmaxf(h.z * s.z + b.z, 0.f);
                v.w = fmaxf(h.w * s.w + b.w, 0.f);
            }
            hs[r][c * 4 + 0] = v.x;
            hs[r][c * 4 + 1] = v.y;
            hs[r][c * 4 + 2] = v.z;
            hs[r][c * 4 + 3] = v.w;
        }
    }
    __syncthreads();

    float4 acc[8];
#pragma unroll
    for (int r = 0; r < 8; r++) acc[r] = make_float4(0.f, 0.f, 0.f, 0.f);
    const float4* Ws4 = (const float4*)Ws;
    for (int k = 0; k < HID; k++) {
        float4 wk = Ws4[k * 16 + fg];
#pragma unroll
        for (int r = 0; r < 8; r++) {
            float h = hs[rg * 8 + r][k];
            acc[r].x += h * wk.x;
            acc[r].y += h * wk.y;
            acc[r].z += h * wk.z;
            acc[r].w += h * wk.w;
        }
    }
    float4* hout4 = (float4*)hout;
#pragma unroll
    for (int r = 0; r < 8; r++) {
        int n = base + rg * 8 + r;
        if (n < N_NODES) {
            float d = dis[n];
            float4 o = acc[r];
            o.x *= d; o.y *= d; o.z *= d; o.w *= d;
            hout4[n * 16 + fg] = o;
        }
    }
}

// ---------------- Aggregation (CSR gather, 4-edge-parallel float4) ----------------

// y[n] = (hw[n] + sum_{j->n} hw[j]) * dis[n] + b ; accumulate sums/sumsq of y
__global__ void aggregate_kernel(const float4* __restrict__ hw4, const int* __restrict__ csrOff,
                                 const int* __restrict__ csrSrc, const float* __restrict__ dis,
                                 const float* __restrict__ bias, float4* __restrict__ y4,
                                 float* __restrict__ sums, float* __restrict__ sumsq) {
    const int lane = threadIdx.x & 63;
    const int wid = threadIdx.x >> 6;
    const int q = lane >> 4;   // edge slot 0..3
    const int fl = lane & 15;  // float4 column within the 64-float row
    const int wave = blockIdx.x * 4 + wid;
    const int nwaves = gridDim.x * 4;

    const float4 bias4 = ((const float4*)bias)[fl];
    float4 s_acc = make_float4(0.f, 0.f, 0.f, 0.f);
    float4 q_acc = make_float4(0.f, 0.f, 0.f, 0.f);

    for (int n = wave; n < N_NODES; n += nwaves) {
        int beg = csrOff[n], end = csrOff[n + 1];
        float4 acc;
        if (q == 0) {
            acc = hw4[n * 16 + fl];  // self loop
        } else {
            acc = make_float4(0.f, 0.f, 0.f, 0.f);
        }
        int e = beg + q;
        int src = 0;
        if (e < end) src = csrSrc[e];
        while (e < end) {
            int cur = src;
            int enext = e + 4;
            if (enext < end) src = csrSrc[enext];  // prefetch next idx
            float4 v = hw4[cur * 16 + fl];
            acc.x += v.x; acc.y += v.y; acc.z += v.z; acc.w += v.w;
            e = enext;
        }
        // reduce across quads
        acc.x += __shfl_xor(acc.x, 16, 64);
        acc.y += __shfl_xor(acc.y, 16, 64);
        acc.z += __shfl_xor(acc.z, 16, 64);
        acc.w += __shfl_xor(acc.w, 16, 64);
        acc.x += __shfl_xor(acc.x, 32, 64);
        acc.y += __shfl_xor(acc.y, 32, 64);
        acc.z += __shfl_xor(acc.z, 32, 64);
        acc.w += __shfl_xor(acc.w, 32, 64);
        if (q == 0) {
            float d = dis[n];
            float4 val;
            val.x = acc.x * d + bias4.x;
            val.y = acc.y * d + bias4.y;
            val.z = acc.z * d + bias4.z;
            val.w = acc.w * d + bias4.w;
            y4[n * 16 + fl] = val;
            s_acc.x += val.x; s_acc.y += val.y; s_acc.z += val.z; s_acc.w += val.w;
            q_acc.x += val.x * val.x; q_acc.y += val.y * val.y;
            q_acc.z += val.z * val.z; q_acc.w += val.w * val.w;
        }
    }
    __shared__ float ls[4][64], lq[4][64];
    ls[wid][lane] = 0.f;
    lq[wid][lane] = 0.f;
    // in-wave ordering: zeros land before values below
    if (q == 0) {
        ls[wid][fl * 4 + 0] = s_acc.x; ls[wid][fl * 4 + 1] = s_acc.y;
        ls[wid][fl * 4 + 2] = s_acc.z; ls[wid][fl * 4 + 3] = s_acc.w;
        lq[wid][fl * 4 + 0] = q_acc.x; lq[wid][fl * 4 + 1] = q_acc.y;
        lq[wid][fl * 4 + 2] = q_acc.z; lq[wid][fl * 4 + 3] = q_acc.w;
    }
    __syncthreads();
    if (wid == 0) {
        float S = ls[0][lane] + ls[1][lane] + ls[2][lane] + ls[3][lane];
        float Q = lq[0][lane] + lq[1][lane] + lq[2][lane] + lq[3][lane];
        atomicAdd(&sums[lane], S);
        atomicAdd(&sumsq[lane], Q);
    }
}

// ---------------- Pool + head ----------------

#define POOL_CHUNK 256
__global__ void pool_kernel(const float* __restrict__ y, const int* __restrict__ batch,
                            const float* __restrict__ scale, const float* __restrict__ shift,
                            float* __restrict__ pool, float* __restrict__ cnt) {
    int f = threadIdx.x & 63;
    int nl = threadIdx.x >> 6;
    int base = blockIdx.x * POOL_CHUNK;
    int endn = min(base + POOL_CHUNK, N_NODES);
    float sc = scale[f], sh = shift[f];
    int g_cur = -1;
    float acc = 0.f;
    float c_acc = 0.f;
    for (int n = base + nl; n < endn; n += 4) {
        int g = batch[n];
        float v = fmaxf(y[n * HID + f] * sc + sh, 0.f);
        if (g != g_cur) {
            if (g_cur >= 0) {
                atomicAdd(&pool[g_cur * HID + f], acc);
                if (f == 0) atomicAdd(&cnt[g_cur], c_acc);
            }
            g_cur = g;
            acc = 0.f;
            c_acc = 0.f;
        }
        acc += v;
        c_acc += 1.f;
    }
    if (g_cur >= 0) {
        atomicAdd(&pool[g_cur * HID + f], acc);
        if (f == 0) atomicAdd(&cnt[g_cur], c_acc);
    }
}

__global__ void head_kernel(const float* __restrict__ pool, const float* __restrict__ cnt,
                            const float* __restrict__ Wc1, const float* __restrict__ bc1,
                            const float* __restrict__ Wc2, const float* __restrict__ bc2,
                            float* __restrict__ out) {
    int g = blockIdx.x;
    int f = threadIdx.x;  // 64 threads
    __shared__ float p[64], z[64];
    float c = fmaxf(cnt[g], 1.0f);
    p[f] = pool[g * HID + f] / c;
    __syncthreads();
    float acc = bc1[f];
    for (int k = 0; k < 64; k++) acc += p[k] * Wc1[k * 64 + f];
    z[f] = fmaxf(acc, 0.f);
    __syncthreads();
    if (f < 2) {
        float o = bc2[f];
        for (int k = 0; k < 64; k++) o += z[k] * Wc2[k * 2 + f];
        out[g * 2 + f] = o;
    }
}

// ---------------- launch ----------------

extern "C" void kernel_launch(void* const* d_in, const int* in_sizes, int n_in,
                              void* d_out, int out_size, void* d_ws, size_t ws_size,
                              hipStream_t stream) {
    const float* x      = (const float*)d_in[0];
    const int*   ei     = (const int*)d_in[1];
    const int*   batch  = (const int*)d_in[2];
    const float* bn_in_g = (const float*)d_in[3];
    const float* bn_in_b = (const float*)d_in[4];
    const float* W0 = (const float*)d_in[5];
    const float* b0 = (const float*)d_in[6];
    const float* g0 = (const float*)d_in[7];
    const float* be0 = (const float*)d_in[8];
    const float* W1 = (const float*)d_in[9];
    const float* b1 = (const float*)d_in[10];
    const float* g1 = (const float*)d_in[11];
    const float* be1 = (const float*)d_in[12];
    const float* W2 = (const float*)d_in[13];
    const float* b2 = (const float*)d_in[14];
    const float* g2 = (const float*)d_in[15];
    const float* be2 = (const float*)d_in[16];
    const float* Wc1 = (const float*)d_in[17];
    const float* bc1 = (const float*)d_in[18];
    const float* Wc2 = (const float*)d_in[19];
    const float* bc2 = (const float*)d_in[20];
    float* out = (float*)d_out;

    char* w = (char*)d_ws;
    size_t off = 0;
    auto take = [&](size_t bytes) {
        size_t r = off;
        off += (bytes + 255) & ~(size_t)255;
        return r;
    };
    // ---- zero region (one memset) ----
    int*   degInt = (int*)(w + take((size_t)N_NODES * 4));
    float* stats  = (float*)(w + take(4 * 256 * 4));  // slot l: [sums 64][sumsq 64][scale 64][shift 64]
    float* pool   = (float*)(w + take((size_t)N_GRAPHS * HID * 4));
    float* cnt    = (float*)(w + take((size_t)N_GRAPHS * 4));
    size_t zero_end = off;
    // ---- rest ----
    float* dis    = (float*)(w + take((size_t)N_NODES * 4));
    int* csrOff   = (int*)(w + take((size_t)(N_NODES + 1) * 4));
    int* cursor   = (int*)(w + take((size_t)N_NODES * 4));
    int* csrSrc   = (int*)(w + take((size_t)N_EDGES * 4));
    int* blockSums  = (int*)(w + take(256 * 4));
    int* blockCarry = (int*)(w + take(256 * 4));
    float* bufA   = (float*)(w + take((size_t)N_NODES * HID * 4));
    float* bufB   = (float*)(w + take((size_t)N_NODES * HID * 4));
    (void)ws_size; (void)n_in; (void)in_sizes; (void)out_size;

    hipMemsetAsync(w, 0, zero_end, stream);

    const int nbN    = (N_NODES + 255) / 256;
    const int nbE    = (N_EDGES + 255) / 256;
    const int nbScan = (N_NODES + 1023) / 1024;  // 98
    const int nbG16  = (N_NODES + GEMM_ROWS - 1) / GEMM_ROWS;
    const int nbG64  = (N_NODES + G64_ROWS - 1) / G64_ROWS;
    const int nbAgg  = 2048;

    // CSR build
    deg_kernel<<<nbE, 256, 0, stream>>>(ei, degInt);
    scan_local<<<nbScan, 1024, 0, stream>>>(degInt, csrOff, blockSums, dis);
    scan_blocksums<<<1, 128, 0, stream>>>(blockSums, blockCarry, nbScan);
    scan_add_carry<<<nbN, 256, 0, stream>>>(csrOff, blockCarry, cursor);
    csr_scatter<<<nbE, 256, 0, stream>>>(ei, cursor, csrSrc);

    float* s0 = stats + 0 * 256;
    float* s1 = stats + 1 * 256;
    float* s2 = stats + 2 * 256;
    float* s3 = stats + 3 * 256;

    // input BN
    stats_x<<<256, 256, 0, stream>>>(x, s0, s0 + 64);
    finalize_bn<<<1, 64, 0, stream>>>(s0, s0 + 64, bn_in_g, bn_in_b, s0 + 128, s0 + 192, IN_DIM);

    // layer 0
    gemm16_kernel<<<nbG16, 256, 0, stream>>>(x, W0, s0 + 128, s0 + 192, dis, bufA);
    aggregate_kernel<<<nbAgg, 256, 0, stream>>>((const float4*)bufA, csrOff, csrSrc, dis, b0,
                                                (float4*)bufB, s1, s1 + 64);
    finalize_bn<<<1, 64, 0, stream>>>(s1, s1 + 64, g0, be0, s1 + 128, s1 + 192, HID);

    // layer 1
    gemm64_kernel<<<nbG64, 256, 0, stream>>>(bufB, W1, s1 + 128, s1 + 192, dis, bufA);
    aggregate_kernel<<<nbAgg, 256, 0, stream>>>((const float4*)bufA, csrOff, csrSrc, dis, b1,
                                                (float4*)bufB, s2, s2 + 64);
    finalize_bn<<<1, 64, 0, stream>>>(s2, s2 + 64, g1, be1, s2 + 128, s2 + 192, HID);

    // layer 2
    gemm64_kernel<<<nbG64, 256, 0, stream>>>(bufB, W2, s2 + 128, s2 + 192, dis, bufA);
    aggregate_kernel<<<nbAgg, 256, 0, stream>>>((const float4*)bufA, csrOff, csrSrc, dis, b2,
                                                (float4*)bufB, s3, s3 + 64);
    finalize_bn<<<1, 64, 0, stream>>>(s3, s3 + 64, g2, be2, s3 + 128, s3 + 192, HID);

    // pool + head
    const int nbPool = (N_NODES + POOL_CHUNK - 1) / POOL_CHUNK;
    pool_kernel<<<nbPool, 256, 0, stream>>>(bufB, batch, s3 + 128, s3 + 192, pool, cnt);
    head_kernel<<<N_GRAPHS, 64, 0, stream>>>(pool, cnt, Wc1, bc1, Wc2, bc2, out);
}

// Round 3
// 546.042 us; speedup vs baseline: 1.6819x; 1.2110x over previous
//
#include <hip/hip_runtime.h>
#include <hip/hip_bf16.h>

#define N_NODES 100000
#define N_EDGES 1200000
#define N_GRAPHS 512
#define HID 64
#define IN_DIM 16
#define EPS 1e-5f

#define NB_BUCKETS 391   // ceil(N_NODES / BUCKET_SPAN)
#define BUCKET_SPAN 256  // dst >> 8
#define REGION 4096      // per-bucket region capacity (avg fill ~3069, +18 sigma)
#define BIN_TILE 4096    // edges per bin block

// ---------------- CSR build (bucketed, LDS-built) ----------------

// Pass 1: partition edges into dst-buckets. Record = src | (dst&255)<<17.
__global__ void bin_kernel(const int* __restrict__ ei, int* __restrict__ bucketCnt,
                           int* __restrict__ regions) {
    __shared__ int hist[NB_BUCKETS], basem[NB_BUCKETS], cur[NB_BUCKETS];
    int t = threadIdx.x;
    for (int i = t; i < NB_BUCKETS; i += 256) { hist[i] = 0; cur[i] = 0; }
    __syncthreads();
    int e0 = blockIdx.x * BIN_TILE;
    int srcs[16], dsts[16];
#pragma unroll
    for (int i = 0; i < 16; i++) {
        int e = e0 + t + i * 256;
        if (e < N_EDGES) {
            srcs[i] = ei[e];
            dsts[i] = ei[N_EDGES + e];
            atomicAdd(&hist[dsts[i] >> 8], 1);
        } else {
            dsts[i] = -1;
        }
    }
    __syncthreads();
    for (int i = t; i < NB_BUCKETS; i += 256) {
        int h = hist[i];
        basem[i] = h ? atomicAdd(&bucketCnt[i], h) : 0;
    }
    __syncthreads();
#pragma unroll
    for (int i = 0; i < 16; i++) {
        if (dsts[i] >= 0) {
            int b = dsts[i] >> 8;
            int pos = basem[b] + atomicAdd(&cur[b], 1);
            if (pos < REGION)
                regions[b * REGION + pos] = srcs[i] | ((dsts[i] & 255) << 17);
        }
    }
}

// Pass 2: exclusive scan of bucket counts -> bucketBase
__global__ void bucket_scan(const int* __restrict__ bucketCnt, int* __restrict__ bucketBase) {
    __shared__ int buf[512];
    int t = threadIdx.x;
    buf[t] = (t < NB_BUCKETS) ? bucketCnt[t] : 0;
    __syncthreads();
    for (int s = 1; s < 512; s <<= 1) {
        int v = (t >= s) ? buf[t - s] : 0;
        __syncthreads();
        buf[t] += v;
        __syncthreads();
    }
    if (t < NB_BUCKETS) bucketBase[t] = (t == 0) ? 0 : buf[t - 1];
    if (t == 0) bucketBase[NB_BUCKETS] = buf[NB_BUCKETS - 1];
}

// Pass 3: per-bucket CSR slice built in LDS, streamed out coalesced.
// Also writes csrOff[n] and dis[n].
__global__ void build_kernel(const int* __restrict__ regions, const int* __restrict__ bucketCnt,
                             const int* __restrict__ bucketBase, int* __restrict__ csrOff,
                             int* __restrict__ csrSrc, float* __restrict__ dis) {
    __shared__ int deg[256], off[256], cur[256];
    __shared__ int slice[REGION];
    int b = blockIdx.x, t = threadIdx.x;
    int cnt = min(bucketCnt[b], REGION);
    int bb = bucketBase[b];
    int nbase = b * BUCKET_SPAN;
    deg[t] = 0;
    __syncthreads();
    for (int i = t; i < cnt; i += 256) {
        int rec = regions[b * REGION + i];
        atomicAdd(&deg[rec >> 17], 1);
    }
    __syncthreads();
    int d = deg[t];
    off[t] = d;
    __syncthreads();
    for (int s = 1; s < 256; s <<= 1) {
        int v = (t >= s) ? off[t - s] : 0;
        __syncthreads();
        off[t] += v;
        __syncthreads();
    }
    int excl = off[t] - d;
    int n = nbase + t;
    if (n < N_NODES) {
        csrOff[n] = bb + excl;
        dis[n] = rsqrtf((float)(d + 1));  // +1 self loop
    }
    if (b == 0 && t == 0) csrOff[N_NODES] = N_EDGES;
    cur[t] = excl;
    __syncthreads();
    for (int i = t; i < cnt; i += 256) {
        int rec = regions[b * REGION + i];
        int pos = atomicAdd(&cur[rec >> 17], 1);
        slice[pos] = rec & 0x1FFFF;
    }
    __syncthreads();
    for (int i = t; i < cnt; i += 256) csrSrc[bb + i] = slice[i];
}

// ---------------- BN statistics ----------------

__global__ void stats_x(const float* __restrict__ x, float* __restrict__ sums,
                        float* __restrict__ sumsq) {
    __shared__ float ls[16], lq[16];
    int t = threadIdx.x;
    if (t < 16) { ls[t] = 0.f; lq[t] = 0.f; }
    __syncthreads();
    float s = 0.f, q = 0.f;
    const int total = N_NODES * IN_DIM;
    for (int i = blockIdx.x * blockDim.x + t; i < total; i += gridDim.x * blockDim.x) {
        float v = x[i];
        s += v; q += v * v;
    }
    int k = t & 15;
    atomicAdd(&ls[k], s);
    atomicAdd(&lq[k], q);
    __syncthreads();
    if (t < 16) { atomicAdd(&sums[t], ls[t]); atomicAdd(&sumsq[t], lq[t]); }
}

__global__ void finalize_bn(const float* __restrict__ sums, const float* __restrict__ sumsq,
                            const float* __restrict__ gamma, const float* __restrict__ beta,
                            float* __restrict__ scale, float* __restrict__ shift, int dim) {
    int t = threadIdx.x;
    if (t < dim) {
        const float invn = 1.0f / (float)N_NODES;
        float m = sums[t] * invn;
        float var = sumsq[t] * invn - m * m;
        float rs = rsqrtf(var + EPS);
        float sc = gamma[t] * rs;
        scale[t] = sc;
        shift[t] = beta[t] - m * sc;
    }
}

// ---------------- GEMMs (BN fused on input read) ----------------

#define GEMM_ROWS 32

__global__ void gemm16_kernel(const float* __restrict__ x, const float* __restrict__ W,
                              const float* __restrict__ scale, const float* __restrict__ shift,
                              const float* __restrict__ dis, float* __restrict__ hout) {
    __shared__ float Ws[IN_DIM][HID];
    __shared__ float xs[GEMM_ROWS][IN_DIM];
    int t = threadIdx.x, f = t & 63, nl = t >> 6;
    for (int i = t; i < IN_DIM * HID; i += 256) Ws[i >> 6][i & 63] = W[i];
    int base = blockIdx.x * GEMM_ROWS;
    for (int i = t; i < GEMM_ROWS * IN_DIM; i += 256) {
        int r = i >> 4, k = i & 15;
        int n = base + r;
        float v = 0.f;
        if (n < N_NODES) v = x[n * IN_DIM + k] * scale[k] + shift[k];
        xs[r][k] = v;
    }
    __syncthreads();
    float acc[8];
#pragma unroll
    for (int r = 0; r < 8; r++) acc[r] = 0.f;
    for (int k = 0; k < IN_DIM; k++) {
        float wk = Ws[k][f];
#pragma unroll
        for (int r = 0; r < 8; r++) acc[r] += xs[r * 4 + nl][k] * wk;
    }
#pragma unroll
    for (int r = 0; r < 8; r++) {
        int n = base + r * 4 + nl;
        if (n < N_NODES) hout[n * HID + f] = acc[r] * dis[n];
    }
}

#define G64_ROWS 128
__global__ void gemm64_kernel(const float* __restrict__ hin, const float* __restrict__ W,
                              const float* __restrict__ scale, const float* __restrict__ shift,
                              const float* __restrict__ dis, float* __restrict__ hout) {
    __shared__ float Ws[HID * HID];          // [k][f], f contiguous
    __shared__ float hs[G64_ROWS][HID + 1];  // +1 pad
    int t = threadIdx.x;
    int fg = t & 15;
    int rg = t >> 4;
    int base = blockIdx.x * G64_ROWS;

    {
        const float4* W4 = (const float4*)W;
        float4* Ws4 = (float4*)Ws;
        for (int i = t; i < HID * HID / 4; i += 256) Ws4[i] = W4[i];
    }
    {
        const float4* hin4 = (const float4*)hin;
        const float4* sc4 = (const float4*)scale;
        const float4* sh4 = (const float4*)shift;
        for (int i = t; i < G64_ROWS * 16; i += 256) {
            int r = i >> 4, c = i & 15;
            int n = base + r;
            float4 v = make_float4(0.f, 0.f, 0.f, 0.f);
            if (n < N_NODES) {
                float4 h = hin4[n * 16 + c];
                float4 s = sc4[c], bsh = sh4[c];
                v.x = fmaxf(h.x * s.x + bsh.x, 0.f);
                v.y = fmaxf(h.y * s.y + bsh.y, 0.f);
                v.z = fmaxf(h.z * s.z + bsh.z, 0.f);
                v.w = fmaxf(h.w * s.w + bsh.w, 0.f);
            }
            hs[r][c * 4 + 0] = v.x;
            hs[r][c * 4 + 1] = v.y;
            hs[r][c * 4 + 2] = v.z;
            hs[r][c * 4 + 3] = v.w;
        }
    }
    __syncthreads();

    float4 acc[8];
#pragma unroll
    for (int r = 0; r < 8; r++) acc[r] = make_float4(0.f, 0.f, 0.f, 0.f);
    const float4* Ws4 = (const float4*)Ws;
    for (int k = 0; k < HID; k++) {
        float4 wk = Ws4[k * 16 + fg];
#pragma unroll
        for (int r = 0; r < 8; r++) {
            float h = hs[rg * 8 + r][k];
            acc[r].x += h * wk.x;
            acc[r].y += h * wk.y;
            acc[r].z += h * wk.z;
            acc[r].w += h * wk.w;
        }
    }
    float4* hout4 = (float4*)hout;
#pragma unroll
    for (int r = 0; r < 8; r++) {
        int n = base + rg * 8 + r;
        if (n < N_NODES) {
            float dsc = dis[n];
            float4 o = acc[r];
            o.x *= dsc; o.y *= dsc; o.z *= dsc; o.w *= dsc;
            hout4[n * 16 + fg] = o;
        }
    }
}

// ---------------- Aggregation (CSR gather, 4-edge-parallel float4) ----------------

__global__ void aggregate_kernel(const float4* __restrict__ hw4, const int* __restrict__ csrOff,
                                 const int* __restrict__ csrSrc, const float* __restrict__ dis,
                                 const float* __restrict__ bias, float4* __restrict__ y4,
                                 float* __restrict__ sums, float* __restrict__ sumsq) {
    const int lane = threadIdx.x & 63;
    const int wid = threadIdx.x >> 6;
    const int q = lane >> 4;   // edge slot 0..3
    const int fl = lane & 15;  // float4 column
    const int wave = blockIdx.x * 4 + wid;
    const int nwaves = gridDim.x * 4;

    const float4 bias4 = ((const float4*)bias)[fl];
    float4 s_acc = make_float4(0.f, 0.f, 0.f, 0.f);
    float4 q_acc = make_float4(0.f, 0.f, 0.f, 0.f);

    for (int n = wave; n < N_NODES; n += nwaves) {
        int beg = csrOff[n], end = csrOff[n + 1];
        float4 acc;
        if (q == 0) {
            acc = hw4[n * 16 + fl];  // self loop
        } else {
            acc = make_float4(0.f, 0.f, 0.f, 0.f);
        }
        int e = beg + q;
        int src = 0;
        if (e < end) src = csrSrc[e];
        while (e < end) {
            int curix = src;
            int enext = e + 4;
            if (enext < end) src = csrSrc[enext];
            float4 v = hw4[curix * 16 + fl];
            acc.x += v.x; acc.y += v.y; acc.z += v.z; acc.w += v.w;
            e = enext;
        }
        acc.x += __shfl_xor(acc.x, 16, 64);
        acc.y += __shfl_xor(acc.y, 16, 64);
        acc.z += __shfl_xor(acc.z, 16, 64);
        acc.w += __shfl_xor(acc.w, 16, 64);
        acc.x += __shfl_xor(acc.x, 32, 64);
        acc.y += __shfl_xor(acc.y, 32, 64);
        acc.z += __shfl_xor(acc.z, 32, 64);
        acc.w += __shfl_xor(acc.w, 32, 64);
        if (q == 0) {
            float d = dis[n];
            float4 val;
            val.x = acc.x * d + bias4.x;
            val.y = acc.y * d + bias4.y;
            val.z = acc.z * d + bias4.z;
            val.w = acc.w * d + bias4.w;
            y4[n * 16 + fl] = val;
            s_acc.x += val.x; s_acc.y += val.y; s_acc.z += val.z; s_acc.w += val.w;
            q_acc.x += val.x * val.x; q_acc.y += val.y * val.y;
            q_acc.z += val.z * val.z; q_acc.w += val.w * val.w;
        }
    }
    __shared__ float ls[4][64], lq[4][64];
    ls[wid][lane] = 0.f;
    lq[wid][lane] = 0.f;
    if (q == 0) {
        ls[wid][fl * 4 + 0] = s_acc.x; ls[wid][fl * 4 + 1] = s_acc.y;
        ls[wid][fl * 4 + 2] = s_acc.z; ls[wid][fl * 4 + 3] = s_acc.w;
        lq[wid][fl * 4 + 0] = q_acc.x; lq[wid][fl * 4 + 1] = q_acc.y;
        lq[wid][fl * 4 + 2] = q_acc.z; lq[wid][fl * 4 + 3] = q_acc.w;
    }
    __syncthreads();
    if (wid == 0) {
        float S = ls[0][lane] + ls[1][lane] + ls[2][lane] + ls[3][lane];
        float Q = lq[0][lane] + lq[1][lane] + lq[2][lane] + lq[3][lane];
        atomicAdd(&sums[lane], S);
        atomicAdd(&sumsq[lane], Q);
    }
}

// ---------------- Pool + head ----------------

#define POOL_CHUNK 256
__global__ void pool_kernel(const float* __restrict__ y, const int* __restrict__ batch,
                            const float* __restrict__ scale, const float* __restrict__ shift,
                            float* __restrict__ pool, float* __restrict__ cnt) {
    int f = threadIdx.x & 63;
    int nl = threadIdx.x >> 6;
    int base = blockIdx.x * POOL_CHUNK;
    int endn = min(base + POOL_CHUNK, N_NODES);
    float sc = scale[f], sh = shift[f];
    int g_cur = -1;
    float acc = 0.f;
    float c_acc = 0.f;
    for (int n = base + nl; n < endn; n += 4) {
        int g = batch[n];
        float v = fmaxf(y[n * HID + f] * sc + sh, 0.f);
        if (g != g_cur) {
            if (g_cur >= 0) {
                atomicAdd(&pool[g_cur * HID + f], acc);
                if (f == 0) atomicAdd(&cnt[g_cur], c_acc);
            }
            g_cur = g;
            acc = 0.f;
            c_acc = 0.f;
        }
        acc += v;
        c_acc += 1.f;
    }
    if (g_cur >= 0) {
        atomicAdd(&pool[g_cur * HID + f], acc);
        if (f == 0) atomicAdd(&cnt[g_cur], c_acc);
    }
}

__global__ void head_kernel(const float* __restrict__ pool, const float* __restrict__ cnt,
                            const float* __restrict__ Wc1, const float* __restrict__ bc1,
                            const float* __restrict__ Wc2, const float* __restrict__ bc2,
                            float* __restrict__ out) {
    int g = blockIdx.x;
    int f = threadIdx.x;  // 64 threads
    __shared__ float p[64], z[64];
    float c = fmaxf(cnt[g], 1.0f);
    p[f] = pool[g * HID + f] / c;
    __syncthreads();
    float acc = bc1[f];
    for (int k = 0; k < 64; k++) acc += p[k] * Wc1[k * 64 + f];
    z[f] = fmaxf(acc, 0.f);
    __syncthreads();
    if (f < 2) {
        float o = bc2[f];
        for (int k = 0; k < 64; k++) o += z[k] * Wc2[k * 2 + f];
        out[g * 2 + f] = o;
    }
}

// ---------------- launch ----------------

extern "C" void kernel_launch(void* const* d_in, const int* in_sizes, int n_in,
                              void* d_out, int out_size, void* d_ws, size_t ws_size,
                              hipStream_t stream) {
    const float* x      = (const float*)d_in[0];
    const int*   ei     = (const int*)d_in[1];
    const int*   batch  = (const int*)d_in[2];
    const float* bn_in_g = (const float*)d_in[3];
    const float* bn_in_b = (const float*)d_in[4];
    const float* W0 = (const float*)d_in[5];
    const float* b0 = (const float*)d_in[6];
    const float* g0 = (const float*)d_in[7];
    const float* be0 = (const float*)d_in[8];
    const float* W1 = (const float*)d_in[9];
    const float* b1 = (const float*)d_in[10];
    const float* g1 = (const float*)d_in[11];
    const float* be1 = (const float*)d_in[12];
    const float* W2 = (const float*)d_in[13];
    const float* b2 = (const float*)d_in[14];
    const float* g2 = (const float*)d_in[15];
    const float* be2 = (const float*)d_in[16];
    const float* Wc1 = (const float*)d_in[17];
    const float* bc1 = (const float*)d_in[18];
    const float* Wc2 = (const float*)d_in[19];
    const float* bc2 = (const float*)d_in[20];
    float* out = (float*)d_out;

    char* w = (char*)d_ws;
    size_t off = 0;
    auto take = [&](size_t bytes) {
        size_t r = off;
        off += (bytes + 255) & ~(size_t)255;
        return r;
    };
    // ---- zero region (one memset) ----
    float* stats  = (float*)(w + take(4 * 256 * 4));
    float* pool   = (float*)(w + take((size_t)N_GRAPHS * HID * 4));
    float* cnt    = (float*)(w + take((size_t)N_GRAPHS * 4));
    int* bucketCnt = (int*)(w + take((size_t)NB_BUCKETS * 4));
    size_t zero_end = off;
    // ---- rest ----
    float* dis    = (float*)(w + take((size_t)N_NODES * 4));
    int* csrOff   = (int*)(w + take((size_t)(N_NODES + 1) * 4));
    int* csrSrc   = (int*)(w + take((size_t)N_EDGES * 4));
    int* bucketBase = (int*)(w + take((size_t)(NB_BUCKETS + 1) * 4));
    float* bufA   = (float*)(w + take((size_t)N_NODES * HID * 4));
    float* bufB   = (float*)(w + take((size_t)N_NODES * HID * 4));
    int* regions  = (int*)bufA;  // alias: regions (6.4 MB) used only before gemm16
    (void)ws_size; (void)n_in; (void)in_sizes; (void)out_size;

    hipMemsetAsync(w, 0, zero_end, stream);

    const int nbBin  = (N_EDGES + BIN_TILE - 1) / BIN_TILE;  // 293
    const int nbG16  = (N_NODES + GEMM_ROWS - 1) / GEMM_ROWS;
    const int nbG64  = (N_NODES + G64_ROWS - 1) / G64_ROWS;
    const int nbAgg  = 2048;

    // CSR build (bucketed)
    bin_kernel<<<nbBin, 256, 0, stream>>>(ei, bucketCnt, regions);
    bucket_scan<<<1, 512, 0, stream>>>(bucketCnt, bucketBase);
    build_kernel<<<NB_BUCKETS, 256, 0, stream>>>(regions, bucketCnt, bucketBase,
                                                 csrOff, csrSrc, dis);

    float* s0 = stats + 0 * 256;
    float* s1 = stats + 1 * 256;
    float* s2 = stats + 2 * 256;
    float* s3 = stats + 3 * 256;

    // input BN
    stats_x<<<256, 256, 0, stream>>>(x, s0, s0 + 64);
    finalize_bn<<<1, 64, 0, stream>>>(s0, s0 + 64, bn_in_g, bn_in_b, s0 + 128, s0 + 192, IN_DIM);

    // layer 0
    gemm16_kernel<<<nbG16, 256, 0, stream>>>(x, W0, s0 + 128, s0 + 192, dis, bufA);
    aggregate_kernel<<<nbAgg, 256, 0, stream>>>((const float4*)bufA, csrOff, csrSrc, dis, b0,
                                                (float4*)bufB, s1, s1 + 64);
    finalize_bn<<<1, 64, 0, stream>>>(s1, s1 + 64, g0, be0, s1 + 128, s1 + 192, HID);

    // layer 1
    gemm64_kernel<<<nbG64, 256, 0, stream>>>(bufB, W1, s1 + 128, s1 + 192, dis, bufA);
    aggregate_kernel<<<nbAgg, 256, 0, stream>>>((const float4*)bufA, csrOff, csrSrc, dis, b1,
                                                (float4*)bufB, s2, s2 + 64);
    finalize_bn<<<1, 64, 0, stream>>>(s2, s2 + 64, g1, be1, s2 + 128, s2 + 192, HID);

    // layer 2
    gemm64_kernel<<<nbG64, 256, 0, stream>>>(bufB, W2, s2 + 128, s2 + 192, dis, bufA);
    aggregate_kernel<<<nbAgg, 256, 0, stream>>>((const float4*)bufA, csrOff, csrSrc, dis, b2,
                                                (float4*)bufB, s3, s3 + 64);
    finalize_bn<<<1, 64, 0, stream>>>(s3, s3 + 64, g2, be2, s3 + 128, s3 + 192, HID);

    // pool + head
    const int nbPool = (N_NODES + POOL_CHUNK - 1) / POOL_CHUNK;
    pool_kernel<<<nbPool, 256, 0, stream>>>(bufB, batch, s3 + 128, s3 + 192, pool, cnt);
    head_kernel<<<N_GRAPHS, 64, 0, stream>>>(pool, cnt, Wc1, bc1, Wc2, bc2, out);
}